// Round 4
// baseline (399.403 us; speedup 1.0000x reference)
//
#include <hip/hip_runtime.h>

typedef __attribute__((ext_vector_type(8))) _Float16 f16x8;
typedef __attribute__((ext_vector_type(4))) float f32x4;

#define S_LEN 2048
#define DMODEL 1024
#define NHEAD 16
#define HD 64
#define QKV_LD 3072
#define BTOT 4
#define LOG2E 1.4426950408889634f

#define GLL16(g, l)                                              \
  __builtin_amdgcn_global_load_lds(                              \
      (const __attribute__((address_space(1))) void*)(g),        \
      (__attribute__((address_space(3))) void*)(l), 16, 0, 0)

// ---------------- fp32 -> fp16 elementwise convert ----------------
__global__ __launch_bounds__(256) void cvt_f32_f16_k(const float* __restrict__ in,
                                                     _Float16* __restrict__ out, int n) {
  int i = (blockIdx.x * 256 + threadIdx.x) * 4;
  int stride = gridDim.x * 256 * 4;
  for (; i < n; i += stride) {
    float4 v = *(const float4*)(in + i);
    _Float16 h[4];
    h[0] = (_Float16)v.x; h[1] = (_Float16)v.y; h[2] = (_Float16)v.z; h[3] = (_Float16)v.w;
    *(uint2*)(out + i) = *(const uint2*)h;
  }
}

// ---------------- fp32 [K][N] -> fp16 [N][K] transpose-convert ----------------
__global__ __launch_bounds__(256) void transpose_cvt_k(const float* __restrict__ W,
                                                       _Float16* __restrict__ Wt,
                                                       int K, int N) {
  __shared__ float t[32][33];
  int n0 = blockIdx.x * 32, k0 = blockIdx.y * 32;
  int tx = threadIdx.x, ty = threadIdx.y;  // (32,8)
#pragma unroll
  for (int i = 0; i < 32; i += 8)
    t[ty + i][tx] = W[(size_t)(k0 + ty + i) * N + n0 + tx];
  __syncthreads();
#pragma unroll
  for (int i = 0; i < 32; i += 8)
    Wt[(size_t)(n0 + ty + i) * K + k0 + tx] = (_Float16)t[tx][ty + i];
}

// ---------------- fp16 GEMM: C[M][N] = A[M][K] * Bt[N][K]^T + bias ----------------
// m97 structure + group-of-8 L2 supertile swizzle.
template <int OUT_F32>
__global__ __launch_bounds__(256) void gemm_bt_k(const _Float16* __restrict__ A,
                                                 const _Float16* __restrict__ Bt,
                                                 const float* __restrict__ bias,
                                                 void* __restrict__ C,
                                                 int M, int N, int K) {
  __shared__ _Float16 As[128 * 32];
  __shared__ _Float16 Bs[128 * 32];
  const int tid = threadIdx.x;
  const int wid = tid >> 6, lane = tid & 63;
  const int quad = lane >> 4, l16 = lane & 15;
  const int wr = wid >> 1, wc = wid & 1;

  // L2 supertile swizzle: 8 consecutive M-blocks share one N-column
  const int lin = blockIdx.y * gridDim.x + blockIdx.x;
  const int width = 8 * gridDim.x;
  const int group = lin / width;
  const int pm = group * 8 + (lin % width) % 8;
  const int pn = (lin % width) / 8;
  const int tm = pm * 128, tn = pn * 128;

  const int sr = tid >> 2;        // 0..63
  const int scc = (tid & 3) * 8;  // 0,8,16,24
  const _Float16* Ag = A + (size_t)(tm + sr) * K + scc;
  const _Float16* Bg = Bt + (size_t)(tn + sr) * K + scc;
  _Float16* AsW = &As[wid * 512];
  _Float16* BsW = &Bs[wid * 512];

  f32x4 acc[4][4] = {};

  for (int k0 = 0; k0 < K; k0 += 32) {
    __syncthreads();
    GLL16(Ag + k0, AsW);
    GLL16(Ag + k0 + (size_t)64 * K, AsW + 2048);
    GLL16(Bg + k0, BsW);
    GLL16(Bg + k0 + (size_t)64 * K, BsW + 2048);
    __syncthreads();

    f16x8 af[4], bf[4];
#pragma unroll
    for (int mt = 0; mt < 4; mt++)
      af[mt] = *(const f16x8*)&As[(wr * 64 + mt * 16 + l16) * 32 + quad * 8];
#pragma unroll
    for (int nt = 0; nt < 4; nt++)
      bf[nt] = *(const f16x8*)&Bs[(wc * 64 + nt * 16 + l16) * 32 + quad * 8];
#pragma unroll
    for (int mt = 0; mt < 4; mt++)
#pragma unroll
      for (int nt = 0; nt < 4; nt++)
        acc[mt][nt] = __builtin_amdgcn_mfma_f32_16x16x32_f16(af[mt], bf[nt], acc[mt][nt], 0, 0, 0);
  }

#pragma unroll
  for (int nt = 0; nt < 4; nt++) {
    int col = tn + wc * 64 + nt * 16 + l16;
    float bv = bias[col];
#pragma unroll
    for (int mt = 0; mt < 4; mt++) {
      int row = tm + wr * 64 + mt * 16 + quad * 4;
#pragma unroll
      for (int r = 0; r < 4; r++) {
        float v = acc[mt][nt][r] + bv;
        if (OUT_F32)
          ((float*)C)[(size_t)(row + r) * N + col] = v;
        else
          ((_Float16*)C)[(size_t)(row + r) * N + col] = (_Float16)v;
      }
    }
  }
}

// ---------------- fused causal flash attention ----------------
// Q-tile 64 (wave = 16 q rows), K-tile 64; S^T/O^T orientation; Q in registers;
// double-buffered K/V prefetch; one barrier per K-tile; grid 2048 blocks.
__global__ __launch_bounds__(256, 3) void attn_k(const _Float16* __restrict__ qkv,
                                                 _Float16* __restrict__ out) {
  __shared__ _Float16 Ks[2][32 * 64 * 2];   // 2 x 8 KB  [k][d]
  __shared__ _Float16 VTs[2][64 * 64];      // 2 x 8 KB  [d][k]
  __shared__ _Float16 Ps[4][16 * 72];       // 9 KB per-wave P^T / epilogue (pitch 72)

  const int tid = threadIdx.x, wid = tid >> 6, lane = tid & 63;
  const int quad = lane >> 4, l16 = lane & 15;
  const int qi = gridDim.x - 1 - blockIdx.x;  // longest-first for causal balance
  const int qt = qi * 64;
  const int bh = blockIdx.y, b = bh >> 4, h = bh & 15;
  const _Float16* base = qkv + (size_t)b * S_LEN * QKV_LD + h * HD;

  // ---- Q fragments in registers (B-operand layout), pre-scaled ----
  f16x8 bq[2];  // [ks]
  {
    const _Float16 qs = (_Float16)(0.125f * LOG2E);
#pragma unroll
    for (int ks = 0; ks < 2; ks++) {
      union { uint4 u; f16x8 h; } v;
      v.u = *(const uint4*)(base + (size_t)(qt + wid * 16 + l16) * QKV_LD + ks * 32 + quad * 8);
      bq[ks] = v.h * qs;
    }
  }

  // K staging via global_load_lds (rows tid>>3 per pass)
  const _Float16* Kg = base + DMODEL + (size_t)(tid >> 3) * QKV_LD + (tid & 7) * 8;
  // V staging (register transpose): kp fast in lane -> 2-way (free) banking
  const int kp = tid & 31, dbase = (tid >> 5) * 8;
  const _Float16* Vg = base + 2 * DMODEL + (size_t)(2 * kp) * QKV_LD + dbase;

  float m_i = -1e30f, l_i = 0.f;
  f32x4 o[4] = {};  // O^T: rows d=md*16+quad*4+r, col q=l16

  const int qmin_w = qt + wid * 16;
  const int nj = qi + 1;

  // ---- prologue: stage tile 0 ----
  uint4 pv0, pv1;
  GLL16(Kg, &Ks[0][wid * 512]);
  GLL16(Kg + (size_t)32 * QKV_LD, &Ks[0][2048 + wid * 512]);
  pv0 = *(const uint4*)(Vg);
  pv1 = *(const uint4*)(Vg + QKV_LD);
  {
    union { uint4 u; _Float16 h[8]; } a, c;
    a.u = pv0; c.u = pv1;
    uint* VT32 = (uint*)VTs[0];
#pragma unroll
    for (int i = 0; i < 8; i++) {
      union { _Float16 h[2]; uint u; } w;
      w.h[0] = a.h[i]; w.h[1] = c.h[i];
      VT32[(dbase + i) * 32 + kp] = w.u;
    }
  }
  __syncthreads();

  for (int j = 0; j < nj; j++) {
    const int cur = j & 1, nxt = cur ^ 1;
    const int k0g = j * 64;
    const bool pf = (j + 1 < nj);
    if (pf) {
      const int kn = k0g + 64;
      GLL16(Kg + (size_t)kn * QKV_LD, &Ks[nxt][wid * 512]);
      GLL16(Kg + (size_t)(kn + 32) * QKV_LD, &Ks[nxt][2048 + wid * 512]);
      pv0 = *(const uint4*)(Vg + (size_t)kn * QKV_LD);
      pv1 = *(const uint4*)(Vg + (size_t)(kn + 1) * QKV_LD);
    }

    // ---- scores: S^T[64k][16q] ----
    f32x4 sc[4] = {};
#pragma unroll
    for (int ks = 0; ks < 2; ks++) {
#pragma unroll
      for (int mt = 0; mt < 4; mt++) {
        f16x8 ak = *(const f16x8*)&Ks[cur][(mt * 16 + l16) * 64 + ks * 32 + quad * 8];
        sc[mt] = __builtin_amdgcn_mfma_f32_16x16x32_f16(ak, bq[ks], sc[mt], 0, 0, 0);
      }
    }

    const bool need_mask = (k0g + 63 > qmin_w);
    const int qg = qmin_w + l16;
    float s[16];
#pragma unroll
    for (int mt = 0; mt < 4; mt++)
#pragma unroll
      for (int r = 0; r < 4; r++) {
        float v = sc[mt][r];
        if (need_mask) {
          int kg = k0g + mt * 16 + quad * 4 + r;
          v = (kg <= qg) ? v : -3.0e38f;
        }
        s[mt * 4 + r] = v;
      }
    float mx = s[0];
#pragma unroll
    for (int i = 1; i < 16; i++) mx = fmaxf(mx, s[i]);
    mx = fmaxf(mx, __shfl_xor(mx, 16, 64));
    mx = fmaxf(mx, __shfl_xor(mx, 32, 64));
    float mnew = fmaxf(m_i, mx);
    float alpha = __builtin_amdgcn_exp2f(m_i - mnew);
    m_i = mnew;
    float rs = 0.f;
    _Float16 ph[16];
#pragma unroll
    for (int i = 0; i < 16; i++) {
      float p = __builtin_amdgcn_exp2f(s[i] - mnew);
      rs += p;
      ph[i] = (_Float16)p;
    }
    rs += __shfl_xor(rs, 16, 64);
    rs += __shfl_xor(rs, 32, 64);
    l_i = l_i * alpha + rs;
    // P^T quad-transpose via per-wave LDS (no barrier: DS wave-ordered)
#pragma unroll
    for (int mt = 0; mt < 4; mt++)
      *(uint2*)&Ps[wid][l16 * 72 + mt * 16 + quad * 4] = *(uint2*)&ph[mt * 4];
#pragma unroll
    for (int md = 0; md < 4; md++) o[md] *= alpha;
    // ---- PV: O^T += V^T · P^T ----
#pragma unroll
    for (int ks = 0; ks < 2; ks++) {
      f16x8 bp = *(const f16x8*)&Ps[wid][l16 * 72 + ks * 32 + quad * 8];
#pragma unroll
      for (int md = 0; md < 4; md++) {
        f16x8 av = *(const f16x8*)&VTs[cur][(md * 16 + l16) * 64 + ks * 32 + quad * 8];
        o[md] = __builtin_amdgcn_mfma_f32_16x16x32_f16(av, bp, o[md], 0, 0, 0);
      }
    }

    if (pf) {
      union { uint4 u; _Float16 h[8]; } a, c;
      a.u = pv0; c.u = pv1;
      uint* VT32 = (uint*)VTs[nxt];
#pragma unroll
      for (int i = 0; i < 8; i++) {
        union { _Float16 h[2]; uint u; } w;
        w.h[0] = a.h[i]; w.h[1] = c.h[i];
        VT32[(dbase + i) * 32 + kp] = w.u;
      }
    }
    __syncthreads();  // drains GLL K(j+1) + V writes; frees cur for next prefetch
  }

  // epilogue: normalize, transpose O^T->O via per-wave LDS, coalesced store
  {
    float inv = 1.0f / l_i;
#pragma unroll
    for (int md = 0; md < 4; md++) {
      _Float16 hh[4];
#pragma unroll
      for (int r = 0; r < 4; r++) hh[r] = (_Float16)(o[md][r] * inv);
      *(uint2*)&Ps[wid][l16 * 72 + md * 16 + quad * 4] = *(uint2*)hh;
    }
  }
  {
    int r = lane >> 2, ch = (lane & 3) * 16;
    const int qg = qt + wid * 16 + r;
    _Float16* orow = out + (size_t)(b * S_LEN + qg) * DMODEL + h * HD + ch;
    *(uint4*)(orow) = *(const uint4*)&Ps[wid][r * 72 + ch];
    *(uint4*)(orow + 8) = *(const uint4*)&Ps[wid][r * 72 + ch + 8];
  }
}

// ---------------- launcher ----------------
extern "C" void kernel_launch(void* const* d_in, const int* in_sizes, int n_in,
                              void* d_out, int out_size, void* d_ws, size_t ws_size,
                              hipStream_t stream) {
  const float* x = (const float*)d_in[0];
  const float* w_attn = (const float*)d_in[1];
  const float* b_attn = (const float*)d_in[2];
  const float* w_proj = (const float*)d_in[3];
  const float* b_proj = (const float*)d_in[4];
  float* outp = (float*)d_out;

  char* ws = (char*)d_ws;
  _Float16* x16 = (_Float16*)ws;                         // 16,777,216 B
  _Float16* wTa = (_Float16*)(ws + 16777216);            //  6,291,456 B
  _Float16* wTp = (_Float16*)(ws + 16777216 + 6291456);  //  2,097,152 B
  _Float16* qkv = (_Float16*)(ws + 25165824);            // 50,331,648 B
  _Float16* abuf = (_Float16*)(ws + 75497472);           // 16,777,216 B

  const int nx = BTOT * S_LEN * DMODEL;

  cvt_f32_f16_k<<<8192, 256, 0, stream>>>(x, x16, nx);
  transpose_cvt_k<<<dim3(QKV_LD / 32, DMODEL / 32), dim3(32, 8), 0, stream>>>(
      w_attn, wTa, DMODEL, QKV_LD);
  transpose_cvt_k<<<dim3(DMODEL / 32, DMODEL / 32), dim3(32, 8), 0, stream>>>(
      w_proj, wTp, DMODEL, DMODEL);

  gemm_bt_k<0><<<dim3(QKV_LD / 128, BTOT * S_LEN / 128), 256, 0, stream>>>(
      x16, wTa, b_attn, qkv, BTOT * S_LEN, QKV_LD, DMODEL);

  attn_k<<<dim3(S_LEN / 64, BTOT * NHEAD), 256, 0, stream>>>(qkv, abuf);

  gemm_bt_k<1><<<dim3(DMODEL / 128, BTOT * S_LEN / 128), 256, 0, stream>>>(
      abuf, wTp, b_proj, outp, BTOT * S_LEN, DMODEL, DMODEL);
}